// Round 1
// 85.211 us; speedup vs baseline: 1.0275x; 1.0275x over previous
//
#include <hip/hip_runtime.h>
#include <hip/hip_bf16.h>

#define BD 2
#define TT 1024
#define HH 8
#define DD 64
#define NLEV 11
#define RT 64
#define NT 16
#define LSTR 72            // LDS row stride (bf16): 144B, proven layout
#define SSTR 65            // fp32 scratch stride
#define NSLOT 15           // per-bh summary slots: 0..6 = H1[m], 7..14 = H0[2m]
#define HSEG 4096          // 64*64 elements per summary

typedef __bf16 bf16;
typedef bf16 bf16x2 __attribute__((ext_vector_type(2)));
typedef bf16 bf16x4 __attribute__((ext_vector_type(4)));
typedef bf16 bf16x8 __attribute__((ext_vector_type(8)));
typedef float floatx4 __attribute__((ext_vector_type(4)));

// ---------------------------------------------------------------------------
// Kernel A: per (bh, m) compute level-1 summary H1[m] over tiles [2m, 2m+2)
// (ref scale = cs end of tile 2m+1) and even level-0 summary H0[2m]
// (ref scale = cs end of tile 2m). m==7 computes only H0[14] (slot 14).
// H[p][d] = sum_j w_j * V[j,p] * K[j,d], w_j = exp(E_ref - cs_j).
// Layout in ws: bf16 H[bh][slot][p*64 + d].
// ---------------------------------------------------------------------------
__global__ __launch_bounds__(512) void hattn_sum_kernel(
    const float* __restrict__ k, const float* __restrict__ v,
    const float* __restrict__ g, bf16* __restrict__ Hws) {
    const int blk = blockIdx.x;
    const int m = blk & 7;
    const int bh = blk >> 3;
    const int b = bh >> 3, h = bh & 7;
    const int tid = threadIdx.x;       // 0..511
    const int lane = tid & 63;
    const int wave = tid >> 6;         // 0..7
    const int grp = wave >> 2;         // tile within the pair
    const int mw = wave & 3;
    const int m0 = mw * 16;
    const int lrow = lane & 15, lk = lane >> 4;
    const int gtid = tid & 255;
    const int jp = gtid >> 3;          // rows 2jp, 2jp+1
    const int p0 = (gtid & 7) * 8;     // dims p0..p0+7

    __shared__ float csS[TT];
    __shared__ float waveTot[8];
    __shared__ bf16 Kt[2][RT * LSTR];
    __shared__ bf16 Vt[2][RT * LSTR];
    __shared__ float scr[RT * SSTR];

    const int ct = 2 * m + grp;        // tile index
    const bool valid = ct < 15;        // m==7, grp==1 has no tile

    // ---- issue K/V tile loads early (independent of the scan) ----
    float4 kA0, kA1, kB0, kB1, vA0, vA1, vB0, vB1;
    if (valid) {
        const int j0 = ct * RT + 2 * jp;
        const float* kp = k + ((size_t)((b * TT + j0) * HH) + h) * DD + p0;
        const float* vp = v + ((size_t)((b * TT + j0) * HH) + h) * DD + p0;
        kA0 = *(const float4*)kp;            kA1 = *(const float4*)(kp + 4);
        kB0 = *(const float4*)(kp + HH*DD);  kB1 = *(const float4*)(kp + HH*DD + 4);
        vA0 = *(const float4*)vp;            vA1 = *(const float4*)(vp + 4);
        vB0 = *(const float4*)(vp + HH*DD);  vB1 = *(const float4*)(vp + HH*DD + 4);
    }

    // ---- cumsum of g[b,:,h] ----
    {
        const float a0 = g[(b * TT + tid * 2) * HH + h];
        const float a1 = g[(b * TT + tid * 2 + 1) * HH + h];
        float s = a0 + a1;
        const float tot = s;
#pragma unroll
        for (int off = 1; off < 64; off <<= 1) {
            const float y = __shfl_up(s, off, 64);
            if (lane >= off) s += y;
        }
        if (lane == 63) waveTot[wave] = s;
        __syncthreads();
        float woff = 0.f;
        for (int w = 0; w < 8; ++w)
            if (w < wave) woff += waveTot[w];
        const float excl = woff + s - tot;
        csS[tid * 2] = excl + a0;
        csS[tid * 2 + 1] = excl + a0 + a1;
    }
    __syncthreads();   // csS visible

    // ---- stage weighted K + V^T (dim-major) ----
    if (valid) {
        const float E = csS[ct * RT + 63];
        const int j0 = ct * RT + 2 * jp;
        const float w0 = __expf(E - csS[j0]);
        const float w1 = __expf(E - csS[j0 + 1]);
        float kr0[8] = {kA0.x, kA0.y, kA0.z, kA0.w, kA1.x, kA1.y, kA1.z, kA1.w};
        float kr1[8] = {kB0.x, kB0.y, kB0.z, kB0.w, kB1.x, kB1.y, kB1.z, kB1.w};
        float vr0[8] = {vA0.x, vA0.y, vA0.z, vA0.w, vA1.x, vA1.y, vA1.z, vA1.w};
        float vr1[8] = {vB0.x, vB0.y, vB0.z, vB0.w, vB1.x, vB1.y, vB1.z, vB1.w};
#pragma unroll
        for (int i2 = 0; i2 < 8; ++i2) {
            bf16x2 kk = {(bf16)(kr0[i2] * w0), (bf16)(kr1[i2] * w1)};
            *(bf16x2*)&Kt[grp][(p0 + i2) * LSTR + 2 * jp] = kk;
            bf16x2 vv = {(bf16)vr0[i2], (bf16)vr1[i2]};
            *(bf16x2*)&Vt[grp][(p0 + i2) * LSTR + 2 * jp] = vv;
        }
    }
    __syncthreads();

    floatx4 acc[4];
#pragma unroll
    for (int nb = 0; nb < 4; ++nb) acc[nb] = (floatx4){0.f, 0.f, 0.f, 0.f};
    if (valid) {
        const bf16x8 a0 = *(bf16x8*)&Vt[grp][(m0 + lrow) * LSTR + lk * 8];
        const bf16x8 a1 = *(bf16x8*)&Vt[grp][(m0 + lrow) * LSTR + 32 + lk * 8];
#pragma unroll
        for (int nb = 0; nb < 4; ++nb) {
            bf16x8 b0 = *(bf16x8*)&Kt[grp][(nb * 16 + lrow) * LSTR + lk * 8];
            bf16x8 b1 = *(bf16x8*)&Kt[grp][(nb * 16 + lrow) * LSTR + 32 + lk * 8];
            acc[nb] = __builtin_amdgcn_mfma_f32_16x16x32_bf16(a0, b0, acc[nb], 0, 0, 0);
            acc[nb] = __builtin_amdgcn_mfma_f32_16x16x32_bf16(a1, b1, acc[nb], 0, 0, 0);
        }
    }
    // grp1 -> fp32 scratch (ref scale = its own tile end == pair end)
    if (grp == 1) {
#pragma unroll
        for (int nb = 0; nb < 4; ++nb)
#pragma unroll
            for (int r = 0; r < 4; ++r)
                scr[(m0 + lk * 4 + r) * SSTR + nb * 16 + lrow] =
                    valid ? acc[nb][r] : 0.f;
    }
    __syncthreads();
    // grp0 combines and writes bf16 summaries to ws
    if (grp == 0) {
        const int te = (m <= 6) ? (2 * m + 2) : 15;
        const float Eend = csS[te * RT - 1];
        const float E0 = csS[(2 * m + 1) * RT - 1];
        const float fac = __expf(Eend - E0);     // m==7: exp(0)=1
        bf16* Hb = Hws + (size_t)bh * NSLOT * HSEG;
        const int slotMain = (m <= 6) ? m : 14;
        const bool alsoH0 = (m <= 6);
#pragma unroll
        for (int nb = 0; nb < 4; ++nb)
#pragma unroll
            for (int r = 0; r < 4; ++r) {
                const int row = m0 + lk * 4 + r;
                const int col = nb * 16 + lrow;
                Hb[slotMain * HSEG + row * 64 + col] =
                    (bf16)(acc[nb][r] * fac + scr[row * SSTR + col]);
                if (alsoH0)
                    Hb[(7 + m) * HSEG + row * 64 + col] = (bf16)acc[nb][r];
            }
    }
}

// ---------------------------------------------------------------------------
// Kernel B: per (bh, rt): diagonal tile (levels 0..6 via per-element P) plus
// levels 7..10 as Q*H piece-blends, H pieces read directly from ws (global).
// Piece decomposition: set bit s of rt covers tiles [t0, t0+2^s) as
// (2^(s-1)) level-1 pieces (s>=1) or one even level-0 piece (s==0); blend
// weight per piece = Lw4[s,row] * exp(cs_row - E_piece_end).
// ---------------------------------------------------------------------------
__global__ __launch_bounds__(512) void hattn_main_kernel(
    const float* __restrict__ q, const float* __restrict__ k,
    const float* __restrict__ v, const float* __restrict__ g,
    const float* __restrict__ L, const bf16* __restrict__ Hws,
    float* __restrict__ out) {
    const int blk = blockIdx.x;
    const int rt = blk & 15;
    const int bh = blk >> 4;
    const int b = bh >> 3, h = bh & 7;
    const int tid = threadIdx.x;       // 0..511
    const int lane = tid & 63;
    const int wave = tid >> 6;         // 0..7
    const int grp = wave >> 2;         // col-half group
    const int mw = wave & 3;           // row strip
    const int m0 = mw * 16;
    const int lrow = lane & 15, lk = lane >> 4;
    const int gtid = tid & 255;
    const int jp = gtid >> 3;
    const int p0 = (gtid & 7) * 8;

    __shared__ float csS[TT];
    __shared__ float waveTot[8];
    __shared__ bf16 Qs[RT * LSTR];     // Q, later aliased as P
    __shared__ bf16 Kt[RT * LSTR];
    __shared__ bf16 Vt[RT * LSTR];
    __shared__ float Lsh[7 * RT];
    __shared__ float Lw4[4 * RT];

    // ---- early diag tile loads: grp0 -> K rows, grp1 -> V rows ----
    float4 xA0, xA1, xB0, xB1;
    {
        const int j0 = rt * RT + 2 * jp;
        const float* bp = (grp == 0 ? k : v) + ((size_t)((b * TT + j0) * HH) + h) * DD + p0;
        xA0 = *(const float4*)bp;
        xA1 = *(const float4*)(bp + 4);
        xB0 = *(const float4*)(bp + HH * DD);
        xB1 = *(const float4*)(bp + HH * DD + 4);
    }

    // ---- cumsum of g[b,:,h] ----
    {
        const float a0 = g[(b * TT + tid * 2) * HH + h];
        const float a1 = g[(b * TT + tid * 2 + 1) * HH + h];
        float s = a0 + a1;
        const float tot = s;
#pragma unroll
        for (int off = 1; off < 64; off <<= 1) {
            const float y = __shfl_up(s, off, 64);
            if (lane >= off) s += y;
        }
        if (lane == 63) waveTot[wave] = s;
        __syncthreads();
        float woff = 0.f;
        for (int w = 0; w < 8; ++w)
            if (w < wave) woff += waveTot[w];
        const float excl = woff + s - tot;
        csS[tid * 2] = excl + a0;
        csS[tid * 2 + 1] = excl + a0 + a1;
    }

    // ---- stage Q + L rows ----
    {
        const int il = tid >> 3, d0 = (tid & 7) * 8;
        const float* qp = q + ((size_t)((b * TT + rt * RT + il) * HH) + h) * DD + d0;
#pragma unroll
        for (int u = 0; u < 8; u += 4) {
            float4 f = *(const float4*)(qp + u);
            bf16x4 w4 = {(bf16)f.x, (bf16)f.y, (bf16)f.z, (bf16)f.w};
            *(bf16x4*)&Qs[il * LSTR + d0 + u] = w4;
        }
    }
    if (tid < 7 * RT) Lsh[tid] = L[((size_t)bh * NLEV + (tid >> 6)) * TT + rt * RT + (tid & 63)];
    if (tid < 4 * RT) Lw4[tid] = L[((size_t)bh * NLEV + 7 + (tid >> 6)) * TT + rt * RT + (tid & 63)];

    // ---- diag staging: grp0 -> K row-major, grp1 -> V^T ----
    if (grp == 0) {
        bf16x4 w0 = {(bf16)xA0.x, (bf16)xA0.y, (bf16)xA0.z, (bf16)xA0.w};
        bf16x4 w1 = {(bf16)xA1.x, (bf16)xA1.y, (bf16)xA1.z, (bf16)xA1.w};
        bf16x4 w2 = {(bf16)xB0.x, (bf16)xB0.y, (bf16)xB0.z, (bf16)xB0.w};
        bf16x4 w3 = {(bf16)xB1.x, (bf16)xB1.y, (bf16)xB1.z, (bf16)xB1.w};
        *(bf16x4*)&Kt[(2 * jp) * LSTR + p0] = w0;
        *(bf16x4*)&Kt[(2 * jp) * LSTR + p0 + 4] = w1;
        *(bf16x4*)&Kt[(2 * jp + 1) * LSTR + p0] = w2;
        *(bf16x4*)&Kt[(2 * jp + 1) * LSTR + p0 + 4] = w3;
    } else {
        float vr0[8] = {xA0.x, xA0.y, xA0.z, xA0.w, xA1.x, xA1.y, xA1.z, xA1.w};
        float vr1[8] = {xB0.x, xB0.y, xB0.z, xB0.w, xB1.x, xB1.y, xB1.z, xB1.w};
#pragma unroll
        for (int i2 = 0; i2 < 8; ++i2) {
            bf16x2 vv = {(bf16)vr0[i2], (bf16)vr1[i2]};
            *(bf16x2*)&Vt[(p0 + i2) * LSTR + 2 * jp] = vv;
        }
    }
    __syncthreads();   // csS, Qs, Kt, Vt, Lsh, Lw4 visible

    const bf16x8 qa0 = *(bf16x8*)&Qs[(m0 + lrow) * LSTR + lk * 8];
    const bf16x8 qa1 = *(bf16x8*)&Qs[(m0 + lrow) * LSTR + 32 + lk * 8];
    float csr[4];
#pragma unroll
    for (int r = 0; r < 4; ++r) csr[r] = csS[rt * RT + m0 + lk * 4 + r];

    // ---- diagonal: S = Q K^T (each wave: 2 col-blocks cb = grp*2 + c) ----
    floatx4 sacc[2];
#pragma unroll
    for (int c = 0; c < 2; ++c) {
        const int cb = grp * 2 + c;
        bf16x8 b0 = *(bf16x8*)&Kt[(cb * 16 + lrow) * LSTR + lk * 8];
        bf16x8 b1 = *(bf16x8*)&Kt[(cb * 16 + lrow) * LSTR + 32 + lk * 8];
        floatx4 a = {0.f, 0.f, 0.f, 0.f};
        a = __builtin_amdgcn_mfma_f32_16x16x32_bf16(qa0, b0, a, 0, 0, 0);
        a = __builtin_amdgcn_mfma_f32_16x16x32_bf16(qa1, b1, a, 0, 0, 0);
        sacc[c] = a;
    }
    __syncthreads();   // all waves done reading qa from Qs before P overwrite

    // per-element weight (levels 0..6) -> P (into Qs; rows by mw, cols by grp)
#pragma unroll
    for (int c = 0; c < 2; ++c) {
        const int jl = (grp * 2 + c) * 16 + lrow;
        const float csj = csS[rt * RT + jl];
#pragma unroll
        for (int r = 0; r < 4; ++r) {
            const int rowl = m0 + lk * 4 + r;
            float wgt = 0.f;
            if (jl <= rowl) {
                const int x = rowl ^ jl;
                const int lev0 = x ? (32 - __clz(x)) : 0;
                wgt = __expf(csr[r] - csj) * Lsh[lev0 * RT + rowl];
            }
            Qs[rowl * LSTR + jl] = (bf16)(sacc[c][r] * wgt);
        }
    }
    __syncthreads();   // P rows assembled from both groups' col-halves

    const bf16x8 pa0 = *(bf16x8*)&Qs[(m0 + lrow) * LSTR + lk * 8];
    const bf16x8 pa1 = *(bf16x8*)&Qs[(m0 + lrow) * LSTR + 32 + lk * 8];
    floatx4 O[2];
#pragma unroll
    for (int c = 0; c < 2; ++c) {
        const int cb = grp * 2 + c;
        bf16x8 b0 = *(bf16x8*)&Vt[(cb * 16 + lrow) * LSTR + lk * 8];
        bf16x8 b1 = *(bf16x8*)&Vt[(cb * 16 + lrow) * LSTR + 32 + lk * 8];
        floatx4 a = {0.f, 0.f, 0.f, 0.f};
        a = __builtin_amdgcn_mfma_f32_16x16x32_bf16(pa0, b0, a, 0, 0, 0);
        a = __builtin_amdgcn_mfma_f32_16x16x32_bf16(pa1, b1, a, 0, 0, 0);
        O[c] = a;
    }

    // ---- hierarchical levels 7..10 from precomputed pieces in ws ----
    const bf16* Hb = Hws + (size_t)bh * NSLOT * HSEG;
    int t0 = 0;
#pragma unroll
    for (int s = 3; s >= 0; --s) {
        if (!((rt >> s) & 1)) continue;
        const int len = 1 << s;
        const int np = (s == 0) ? 1 : (len >> 1);
        for (int u = 0; u < np; ++u) {
            int slot, te;
            if (s == 0) {
                slot = 7 + (t0 >> 1);      // H0[t0], t0 even
                te = t0 + 1;
            } else {
                const int mm = (t0 >> 1) + u;  // H1[mm] over tiles [2mm, 2mm+2)
                slot = mm;
                te = 2 * mm + 2;
            }
            const float Em = csS[te * RT - 1];
            float wr[4];
#pragma unroll
            for (int r = 0; r < 4; ++r)
                wr[r] = Lw4[s * RT + m0 + lk * 4 + r] * __expf(csr[r] - Em);
            const bf16* Hp = Hb + slot * HSEG;
#pragma unroll
            for (int c = 0; c < 2; ++c) {
                const int cb = grp * 2 + c;
                bf16x8 b0 = *(const bf16x8*)&Hp[(cb * 16 + lrow) * 64 + lk * 8];
                bf16x8 b1 = *(const bf16x8*)&Hp[(cb * 16 + lrow) * 64 + 32 + lk * 8];
                floatx4 a = {0.f, 0.f, 0.f, 0.f};
                a = __builtin_amdgcn_mfma_f32_16x16x32_bf16(qa0, b0, a, 0, 0, 0);
                a = __builtin_amdgcn_mfma_f32_16x16x32_bf16(qa1, b1, a, 0, 0, 0);
#pragma unroll
                for (int r = 0; r < 4; ++r) O[c][r] += wr[r] * a[r];
            }
        }
        t0 += len;
    }

    // ---- epilogue: rows by mw strip, cols by grp half ----
#pragma unroll
    for (int r = 0; r < 4; ++r) {
        const int ig = rt * RT + m0 + lk * 4 + r;
        float* op = out + ((size_t)((b * TT + ig) * HH) + h) * DD;
#pragma unroll
        for (int c = 0; c < 2; ++c)
            op[(grp * 2 + c) * 16 + lrow] = O[c][r];
    }
}

extern "C" void kernel_launch(void* const* d_in, const int* in_sizes, int n_in,
                              void* d_out, int out_size, void* d_ws, size_t ws_size,
                              hipStream_t stream) {
    const float* q = (const float*)d_in[0];
    const float* k = (const float*)d_in[1];
    const float* v = (const float*)d_in[2];
    const float* g = (const float*)d_in[3];
    const float* L = (const float*)d_in[4];
    float* out = (float*)d_out;
    bf16* Hws = (bf16*)d_ws;   // 16 * 15 * 4096 * 2B = 1.92 MB << ws_size

    hattn_sum_kernel<<<16 * 8, 512, 0, stream>>>(k, v, g, Hws);
    hattn_main_kernel<<<BD * HH * NT, 512, 0, stream>>>(q, k, v, g, L, Hws, out);
}